// Round 11
// baseline (65.667 us; speedup 1.0000x reference)
//
#include <hip/hip_runtime.h>
#include <hip/hip_bf16.h>

// DCNv2 fwd — barrier-free, LDS-free main loop: lerp output registers ARE the
// MFMA B-fragments (lane (lg,lr) samples pixel lr, channels ks*32+lg*8..+7).
// B=8, C=64, H=W=96, O=64, K=3, s=1, p=1, d=1, DG=1 -> Ho=Wo=96.
// R11: removes the per-iter ds_write->ds_read lgkmcnt chain that R7-R10's
// prefetch pinning couldn't fix. LDS used only for the epilogue transpose.

#define B_   8
#define C_   64
#define H_   96
#define W_   96
#define O_   64
#define KK_  9
#define HW_  (H_ * W_)          // 9216
#define NTILE (HW_ / 64)        // 144

typedef __attribute__((ext_vector_type(8))) short short8;     // 8 bf16
typedef __attribute__((ext_vector_type(4))) float f32x4;
typedef __attribute__((ext_vector_type(4))) unsigned uint4v;

__device__ __forceinline__ unsigned short f2bf(float f) {
    union { float f; unsigned u; } v; v.f = f;
    unsigned r = v.u + 0x7FFF + ((v.u >> 16) & 1);   // RNE
    return (unsigned short)(r >> 16);
}
__device__ __forceinline__ float bflo(unsigned u) {
    union { unsigned u; float f; } v; v.u = u << 16; return v.f;
}
__device__ __forceinline__ float bfhi(unsigned u) {
    union { unsigned u; float f; } v; v.u = u & 0xffff0000u; return v.f;
}
__device__ __forceinline__ unsigned packbf2(float lo, float hi) {
    __hip_bfloat162 h = __float22bfloat162_rn(make_float2(lo, hi));
    union { __hip_bfloat162 h; unsigned u; } v; v.h = h; return v.u;
}

// ---- converter: x NCHW f32 -> NHWC bf16 (barrier-free, no LDS);
//      blocks 0..15 additionally emit fragment-ordered bf16 weights ----
__global__ __launch_bounds__(256)
void cvt_kernel(const float* __restrict__ x, const float* __restrict__ wgt,
                unsigned short* __restrict__ xT, unsigned short* __restrict__ wsb)
{
    const int t = threadIdx.x;
    if (blockIdx.x < 16) {
        int i = blockIdx.x * 256 + t;      // (o,c) over 4096
        int o = i >> 6, c = i & 63;
        int ks = c >> 5, hi = (c >> 3) & 3, j = c & 7;
        #pragma unroll
        for (int kk = 0; kk < KK_; ++kk)
            wsb[(size_t)(((kk*2 + ks)*4 + hi)*64 + o)*8 + j] =
                f2bf(wgt[(size_t)(o*64 + c)*KK_ + kk]);
    }
    const int b  = blockIdx.x & 7;                 // XCD-pinned
    const int px = (blockIdx.x >> 3) * 256 + t;    // 36 blk/img * 256 = 9216
    const float* xs = x + (size_t)b * C_ * HW_ + px;
    unsigned pk[32];
    #pragma unroll
    for (int c2 = 0; c2 < 32; ++c2) {
        float lo = xs[(size_t)(2*c2)   * HW_];
        float hi = xs[(size_t)(2*c2+1) * HW_];
        pk[c2] = packbf2(lo, hi);
    }
    uint4v* dst = (uint4v*)(xT + ((size_t)b * HW_ + px) * C_);
    #pragma unroll
    for (int j = 0; j < 8; ++j) {
        uint4v v;
        v.x = pk[4*j]; v.y = pk[4*j+1]; v.z = pk[4*j+2]; v.w = pk[4*j+3];
        dst[j] = v;
    }
}

// LDS: epilogue transpose only, [64 o][68 f32] = 17408 B
__global__ __launch_bounds__(256, 2)
void dcn_mfma(const unsigned short* __restrict__ xT,
              const float* __restrict__ offs, const float* __restrict__ mask,
              const unsigned short* __restrict__ wsb,
              const float* __restrict__ bias, float* __restrict__ out)
{
    __shared__ __align__(16) float outb[64 * 68];

    const int t    = threadIdx.x;
    const int lane = t & 63;
    const int wid  = t >> 6;
    const int bi   = blockIdx.x & 7;              // XCD-pinned
    const int tile = blockIdx.x >> 3;
    const int pixbase = tile * 64;

    const int lr = lane & 15, lg = lane >> 4;     // fragment coords
    // this lane samples pixel lr of the wave's 16-px tile, channel slice lg*8
    const int pix = pixbase + wid * 16 + lr;
    const int ho = pix / W_, wo = pix % W_;
    const float* offp = offs + (size_t)bi * 18 * HW_ + pix;
    const float* mp   = mask + (size_t)bi * 9  * HW_ + pix;
    const unsigned short* xb = xT + (size_t)bi * HW_ * C_ + lg * 8;

    f32x4 acc[4] = {};                            // 4 o-tiles x (16o x 16px)

    float coy[2], cox[2], cmv[2];
    uint4v cor[2][8];                             // [slot][corner*2 + ks]
    float  cw[2][4];

    coy[0] = offp[0];          cox[0] = offp[HW_];       cmv[0] = mp[0];
    coy[1] = offp[2 * HW_];    cox[1] = offp[3 * HW_];   cmv[1] = mp[HW_];

    auto geom_issue = [&](int k, int s) {
        float py  = (float)(ho - 1 + k / 3) + coy[s];
        float pxf = (float)(wo - 1 + k % 3) + cox[s];
        float y0f = floorf(py), x0f = floorf(pxf);
        float ly = py - y0f, lx = pxf - x0f;
        int y0 = (int)y0f, x0 = (int)x0f;
        int y1 = y0 + 1, x1 = x0 + 1;
        float hy = 1.f - ly, hx = 1.f - lx;
        float mv = cmv[s];
        bool oky0 = (y0 >= 0) & (y0 < H_), oky1 = (y1 >= 0) & (y1 < H_);
        bool okx0 = (x0 >= 0) & (x0 < W_), okx1 = (x1 >= 0) & (x1 < W_);
        cw[s][0] = hy * hx * mv * ((oky0 & okx0) ? 1.f : 0.f);
        cw[s][1] = hy * lx * mv * ((oky0 & okx1) ? 1.f : 0.f);
        cw[s][2] = ly * hx * mv * ((oky1 & okx0) ? 1.f : 0.f);
        cw[s][3] = ly * lx * mv * ((oky1 & okx1) ? 1.f : 0.f);
        int iy0 = min(max(y0, 0), H_ - 1), iy1 = min(max(y1, 0), H_ - 1);
        int ix0 = min(max(x0, 0), W_ - 1), ix1 = min(max(x1, 0), W_ - 1);
        const uint4v* a00 = (const uint4v*)(xb + (size_t)(iy0 * W_ + ix0) * C_);
        const uint4v* a01 = (const uint4v*)(xb + (size_t)(iy0 * W_ + ix1) * C_);
        const uint4v* a10 = (const uint4v*)(xb + (size_t)(iy1 * W_ + ix0) * C_);
        const uint4v* a11 = (const uint4v*)(xb + (size_t)(iy1 * W_ + ix1) * C_);
        cor[s][0] = a00[0]; cor[s][1] = a00[4];   // ks0: ch lg*8, ks1: +32 ch
        cor[s][2] = a01[0]; cor[s][3] = a01[4];
        cor[s][4] = a10[0]; cor[s][5] = a10[4];
        cor[s][6] = a11[0]; cor[s][7] = a11[4];
    };

    geom_issue(0, 0);                             // prologue: corners(0) in flight

    #pragma unroll
    for (int kk = 0; kk < KK_; ++kk) {
        const int cur = kk & 1, nxt = cur ^ 1;

        // A-frags(kk): issue first, consumed at the bottom (~300 cy cover)
        short8 af[8];
        #pragma unroll
        for (int ks = 0; ks < 2; ++ks)
            #pragma unroll
            for (int m = 0; m < 4; ++m)
                af[ks * 4 + m] = *(const short8*)(wsb +
                    (size_t)((((kk * 2 + ks) * 4 + lg) * 64) + m * 16 + lr) * 8);

        // coords(kk+2): 2-deep prefetch (slot cur was consumed last iter)
        if (kk + 2 < KK_) {
            coy[cur] = offp[(size_t)(2 * kk + 4) * HW_];
            cox[cur] = offp[(size_t)(2 * kk + 5) * HW_];
            cmv[cur] = mp[(size_t)(kk + 2) * HW_];
        }
        // corners(kk+1): 1-deep prefetch (full iteration of latency cover)
        if (kk + 1 < KK_) geom_issue(kk + 1, nxt);

        // PIN: next-iter corner loads must issue before this iter's compute
        __builtin_amdgcn_sched_barrier(0);

        // lerp corners(kk) -> B-fragments directly (no LDS round-trip)
        float w00 = cw[cur][0], w01 = cw[cur][1];
        float w10 = cw[cur][2], w11 = cw[cur][3];
        union { uint4v u; short8 s; } b0, b1;
        #pragma unroll
        for (int ks = 0; ks < 2; ++ks) {
            #pragma unroll
            for (int j = 0; j < 4; ++j) {
                unsigned u0 = cor[cur][0 + ks][j];
                unsigned u1 = cor[cur][2 + ks][j];
                unsigned u2 = cor[cur][4 + ks][j];
                unsigned u3 = cor[cur][6 + ks][j];
                float lo = fmaf(bflo(u0), w00, fmaf(bflo(u1), w01,
                           fmaf(bflo(u2), w10, bflo(u3) * w11)));
                float hi = fmaf(bfhi(u0), w00, fmaf(bfhi(u1), w01,
                           fmaf(bfhi(u2), w10, bfhi(u3) * w11)));
                if (ks == 0) b0.u[j] = packbf2(lo, hi);
                else         b1.u[j] = packbf2(lo, hi);
            }
        }

        // MFMA: the lerped registers are the B-operand
        #pragma unroll
        for (int m = 0; m < 4; ++m)
            acc[m] = __builtin_amdgcn_mfma_f32_16x16x32_bf16(af[m],     b0.s, acc[m], 0, 0, 0);
        #pragma unroll
        for (int m = 0; m < 4; ++m)
            acc[m] = __builtin_amdgcn_mfma_f32_16x16x32_bf16(af[4 + m], b1.s, acc[m], 0, 0, 0);
    }

    // ---- epilogue: LDS transpose -> float4 full-line coalesced stores ----
    // acc C/D layout: col = lr (pixel), row o = m*16 + lg*4 + r
    #pragma unroll
    for (int m = 0; m < 4; ++m)
        #pragma unroll
        for (int r = 0; r < 4; ++r)
            outb[(m * 16 + lg * 4 + r) * 68 + wid * 16 + lr] = acc[m][r];
    __syncthreads();
    #pragma unroll
    for (int r = 0; r < 4; ++r) {
        int idx = t + 256 * r;                    // 1024 float4 chunks
        int o = idx >> 4, pq = (idx & 15) * 4;
        float4 v = *(const float4*)&outb[o * 68 + pq];
        float bv = bias[o];
        v.x += bv; v.y += bv; v.z += bv; v.w += bv;
        *(float4*)&out[((size_t)bi * O_ + o) * HW_ + pixbase + pq] = v;
    }
}

extern "C" void kernel_launch(void* const* d_in, const int* in_sizes, int n_in,
                              void* d_out, int out_size, void* d_ws, size_t ws_size,
                              hipStream_t stream)
{
    const float* x    = (const float*)d_in[0];
    const float* offs = (const float*)d_in[1];
    const float* mask = (const float*)d_in[2];
    const float* wgt  = (const float*)d_in[3];
    const float* bias = (const float*)d_in[4];
    float* out = (float*)d_out;

    unsigned short* xT  = (unsigned short*)d_ws;                     // 9,437,184 B
    unsigned short* wsb = (unsigned short*)((char*)d_ws + 9437184);  // 73,728 B

    hipLaunchKernelGGL(cvt_kernel, dim3(288), dim3(256), 0, stream,
                       x, wgt, xT, wsb);
    hipLaunchKernelGGL(dcn_mfma, dim3(B_ * NTILE), dim3(256), 0, stream,
                       xT, offs, mask, wsb, bias, out);
}

// Round 12
// 42.722 us; speedup vs baseline: 1.5371x; 1.5371x over previous
//
#include <hip/hip_runtime.h>
#include <hip/hip_bf16.h>

// DCNv2 fwd — bf16 MFMA, VMEM-bandwidth-optimized.
// B=8, C=64, H=W=96, O=64, K=3, s=1, p=1, d=1, DG=1 -> Ho=Wo=96.
// R12: (1) weights staged in LDS once per block-iter (was: 4 waves re-reading
// the same 8KB/iter from global -> half the VMEM bytes); (2) dense pixel-major
// corner loads: each instr reads 8 FULL 128B lines (was 16 half lines);
// (3) one __syncthreads/iter for weight dbuf visibility.

#define B_   8
#define C_   64
#define H_   96
#define W_   96
#define O_   64
#define KK_  9
#define HW_  (H_ * W_)          // 9216
#define NTILE (HW_ / 64)        // 144

typedef __attribute__((ext_vector_type(8))) short short8;     // 8 bf16
typedef __attribute__((ext_vector_type(4))) float f32x4;
typedef __attribute__((ext_vector_type(4))) unsigned uint4v;

__device__ __forceinline__ unsigned short f2bf(float f) {
    union { float f; unsigned u; } v; v.f = f;
    unsigned r = v.u + 0x7FFF + ((v.u >> 16) & 1);   // RNE
    return (unsigned short)(r >> 16);
}
__device__ __forceinline__ float bflo(unsigned u) {
    union { unsigned u; float f; } v; v.u = u << 16; return v.f;
}
__device__ __forceinline__ float bfhi(unsigned u) {
    union { unsigned u; float f; } v; v.u = u & 0xffff0000u; return v.f;
}
__device__ __forceinline__ unsigned packbf2(float lo, float hi) {
    __hip_bfloat162 h = __float22bfloat162_rn(make_float2(lo, hi));
    union { __hip_bfloat162 h; unsigned u; } v; v.h = h; return v.u;
}

// ---- converter: x NCHW f32 -> NHWC bf16 (barrier-free, no LDS);
//      blocks 0..15 additionally emit fragment-ordered bf16 weights ----
__global__ __launch_bounds__(256)
void cvt_kernel(const float* __restrict__ x, const float* __restrict__ wgt,
                unsigned short* __restrict__ xT, unsigned short* __restrict__ wsb)
{
    const int t = threadIdx.x;
    if (blockIdx.x < 16) {
        int i = blockIdx.x * 256 + t;      // (o,c) over 4096
        int o = i >> 6, c = i & 63;
        int ks = c >> 5, hi = (c >> 3) & 3, j = c & 7;
        #pragma unroll
        for (int kk = 0; kk < KK_; ++kk)
            wsb[(size_t)(((kk*2 + ks)*4 + hi)*64 + o)*8 + j] =
                f2bf(wgt[(size_t)(o*64 + c)*KK_ + kk]);
    }
    const int b  = blockIdx.x & 7;                 // XCD-pinned
    const int px = (blockIdx.x >> 3) * 256 + t;    // 36 blk/img * 256 = 9216
    const float* xs = x + (size_t)b * C_ * HW_ + px;
    unsigned pk[32];
    #pragma unroll
    for (int c2 = 0; c2 < 32; ++c2) {
        float lo = xs[(size_t)(2*c2)   * HW_];
        float hi = xs[(size_t)(2*c2+1) * HW_];
        pk[c2] = packbf2(lo, hi);
    }
    uint4v* dst = (uint4v*)(xT + ((size_t)b * HW_ + px) * C_);
    #pragma unroll
    for (int j = 0; j < 8; ++j) {
        uint4v v;
        v.x = pk[4*j]; v.y = pk[4*j+1]; v.z = pk[4*j+2]; v.w = pk[4*j+3];
        dst[j] = v;
    }
}

// LDS map: stg 4 waves x 2048 B (16px x 128B, XOR-swz)        [0, 8192)
//          wl  weight dbuf 2 x 8192 B (fragment-ordered)      [8192, 24576)
//          epilogue outb [64 o][68 f32] aliases [0, 17408)  (after barrier)
__global__ __launch_bounds__(256, 4)
void dcn_mfma(const unsigned short* __restrict__ xT,
              const float* __restrict__ offs, const float* __restrict__ mask,
              const unsigned short* __restrict__ wsb,
              const float* __restrict__ bias, float* __restrict__ out)
{
    __shared__ __align__(16) char lds[24576];
    char* stg = lds + (threadIdx.x >> 6) * 2048;   // wave-private samples
    char* wl0 = lds + 8192;                        // weight double-buffer

    const int t    = threadIdx.x;
    const int lane = t & 63;
    const int wid  = t >> 6;
    const int bi   = blockIdx.x & 7;               // XCD-pinned
    const int tile = blockIdx.x >> 3;
    const int pixbase = tile * 64;

    const int lr = lane & 15, lg = lane >> 4;      // MFMA fragment coords
    const int s   = lane & 7;                      // 16B slice within line
    const int ph0 = lane >> 3;                     // pixel (h=0); h=1 adds 8
    const int pix0 = pixbase + wid * 16 + ph0;

    const float* offB = offs + (size_t)bi * 18 * HW_;
    const float* mB   = mask + (size_t)bi * 9  * HW_;
    const unsigned short* xB = xT + (size_t)bi * HW_ * C_;

    f32x4 acc[4] = {};                             // 4 o-tiles x (16o x 16px)

    // coords for current kk, both pixel halves
    float cy[2], cx[2], cm[2];
    #pragma unroll
    for (int h = 0; h < 2; ++h) {
        cy[h] = offB[pix0 + h * 8];
        cx[h] = offB[HW_ + pix0 + h * 8];
        cm[h] = mB[pix0 + h * 8];
    }

    // prologue: stage weights kk=0 into wl[0]
    {
        const uint4v* g = (const uint4v*)(wsb + (size_t)t * 16);
        char* d = wl0 + t * 32;
        uint4v g0 = g[0], g1 = g[1];
        *(uint4v*)d = g0; *(uint4v*)(d + 16) = g1;
    }

    #pragma unroll 1
    for (int kk = 0; kk < KK_; ++kk) {
        const int cur = kk & 1, nxt = cur ^ 1;
        __syncthreads();   // wl[cur] staged by all; wl[nxt] free to overwrite

        // ---- geometry + DENSE corner loads (8 instrs x 8 full lines) ----
        uint4v cor[2][4];
        float  w4[2][4];
        #pragma unroll
        for (int h = 0; h < 2; ++h) {
            int pixg = pix0 + h * 8;
            int ho = pixg / W_, wo = pixg % W_;
            float py  = (float)(ho - 1 + kk / 3) + cy[h];
            float pxf = (float)(wo - 1 + kk % 3) + cx[h];
            float y0f = floorf(py), x0f = floorf(pxf);
            float ly = py - y0f, lx = pxf - x0f;
            int y0 = (int)y0f, x0 = (int)x0f;
            int y1 = y0 + 1, x1 = x0 + 1;
            float hy = 1.f - ly, hx = 1.f - lx;
            float mv = cm[h];
            bool oky0 = (y0 >= 0) & (y0 < H_), oky1 = (y1 >= 0) & (y1 < H_);
            bool okx0 = (x0 >= 0) & (x0 < W_), okx1 = (x1 >= 0) & (x1 < W_);
            w4[h][0] = hy * hx * mv * ((oky0 & okx0) ? 1.f : 0.f);
            w4[h][1] = hy * lx * mv * ((oky0 & okx1) ? 1.f : 0.f);
            w4[h][2] = ly * hx * mv * ((oky1 & okx0) ? 1.f : 0.f);
            w4[h][3] = ly * lx * mv * ((oky1 & okx1) ? 1.f : 0.f);
            int iy0 = min(max(y0, 0), H_ - 1), iy1 = min(max(y1, 0), H_ - 1);
            int ix0 = min(max(x0, 0), W_ - 1), ix1 = min(max(x1, 0), W_ - 1);
            cor[h][0] = *(const uint4v*)(xB + (size_t)(iy0*W_ + ix0)*C_ + s*8);
            cor[h][1] = *(const uint4v*)(xB + (size_t)(iy0*W_ + ix1)*C_ + s*8);
            cor[h][2] = *(const uint4v*)(xB + (size_t)(iy1*W_ + ix0)*C_ + s*8);
            cor[h][3] = *(const uint4v*)(xB + (size_t)(iy1*W_ + ix1)*C_ + s*8);
        }

        // ---- stage weights kk+1 -> wl[nxt] (cooperative, dense) ----
        if (kk + 1 < KK_) {
            const uint4v* g = (const uint4v*)(wsb + (size_t)(kk+1)*4096 + t*16);
            char* d = wl0 + nxt * 8192 + t * 32;
            uint4v g0 = g[0], g1 = g[1];
            *(uint4v*)d = g0; *(uint4v*)(d + 16) = g1;
        }

        // ---- coords prefetch kk+1 ----
        if (kk + 1 < KK_) {
            #pragma unroll
            for (int h = 0; h < 2; ++h) {
                cy[h] = offB[(size_t)(2*kk + 2) * HW_ + pix0 + h * 8];
                cx[h] = offB[(size_t)(2*kk + 3) * HW_ + pix0 + h * 8];
                cm[h] = mB[(size_t)(kk + 1) * HW_ + pix0 + h * 8];
            }
        }

        // ---- lerp (lane-local slice) + pack + swizzled ds_write ----
        #pragma unroll
        for (int h = 0; h < 2; ++h) {
            float w00 = w4[h][0], w01 = w4[h][1];
            float w10 = w4[h][2], w11 = w4[h][3];
            uint4v pk4;
            #pragma unroll
            for (int j = 0; j < 4; ++j) {
                unsigned u0 = cor[h][0][j], u1 = cor[h][1][j];
                unsigned u2 = cor[h][2][j], u3 = cor[h][3][j];
                float lo = fmaf(bflo(u0), w00, fmaf(bflo(u1), w01,
                           fmaf(bflo(u2), w10, bflo(u3) * w11)));
                float hi = fmaf(bfhi(u0), w00, fmaf(bfhi(u1), w01,
                           fmaf(bfhi(u2), w10, bfhi(u3) * w11)));
                pk4[j] = packbf2(lo, hi);
            }
            int pxl = ph0 + h * 8;
            *(uint4v*)(stg + pxl * 128 + ((s * 16) ^ ((pxl & 7) << 4))) = pk4;
        }

        // ---- B-frags (own-wave LDS, in-order DS) + A-frags + MFMA ----
        union { uint4v u; short8 s8; } b0, b1;
        b0.u = *(const uint4v*)(stg + lr*128 + (( lg*16      ) ^ ((lr & 7) << 4)));
        b1.u = *(const uint4v*)(stg + lr*128 + (((64 + lg*16)) ^ ((lr & 7) << 4)));
        const char* wlc = wl0 + cur * 8192;
        #pragma unroll
        for (int ks = 0; ks < 2; ++ks)
            #pragma unroll
            for (int m = 0; m < 4; ++m) {
                short8 a = *(const short8*)(wlc +
                    (((ks*4 + lg) * 64 + m*16 + lr) << 4));
                acc[m] = __builtin_amdgcn_mfma_f32_16x16x32_bf16(
                             a, ks ? b1.s8 : b0.s8, acc[m], 0, 0, 0);
            }
    }

    // ---- epilogue: LDS transpose -> float4 full-line coalesced stores ----
    __syncthreads();                     // everyone done with stg/wl before alias
    float* outb = (float*)lds;           // [64 o][68 f32] = 17408 B
    #pragma unroll
    for (int m = 0; m < 4; ++m)
        #pragma unroll
        for (int r = 0; r < 4; ++r)
            outb[(m * 16 + lg * 4 + r) * 68 + wid * 16 + lr] = acc[m][r];
    __syncthreads();
    #pragma unroll
    for (int r = 0; r < 4; ++r) {
        int idx = t + 256 * r;           // 1024 float4 chunks
        int o = idx >> 4, pq = (idx & 15) * 4;
        float4 v = *(const float4*)&outb[o * 68 + pq];
        float bv = bias[o];
        v.x += bv; v.y += bv; v.z += bv; v.w += bv;
        *(float4*)&out[((size_t)bi * O_ + o) * HW_ + pixbase + pq] = v;
    }
}

extern "C" void kernel_launch(void* const* d_in, const int* in_sizes, int n_in,
                              void* d_out, int out_size, void* d_ws, size_t ws_size,
                              hipStream_t stream)
{
    const float* x    = (const float*)d_in[0];
    const float* offs = (const float*)d_in[1];
    const float* mask = (const float*)d_in[2];
    const float* wgt  = (const float*)d_in[3];
    const float* bias = (const float*)d_in[4];
    float* out = (float*)d_out;

    unsigned short* xT  = (unsigned short*)d_ws;                     // 9,437,184 B
    unsigned short* wsb = (unsigned short*)((char*)d_ws + 9437184);  // 73,728 B

    hipLaunchKernelGGL(cvt_kernel, dim3(288), dim3(256), 0, stream,
                       x, wgt, xT, wsb);
    hipLaunchKernelGGL(dcn_mfma, dim3(B_ * NTILE), dim3(256), 0, stream,
                       xT, offs, mask, wsb, bias, out);
}